// Round 2
// baseline (688.722 us; speedup 1.0000x reference)
//
#include <hip/hip_runtime.h>

// VectorQuantizer on MI355X.
// d_out is FLOAT32 (forensically confirmed round 1), concatenated:
// [0]=vq_loss, [1]=commitment_loss, [2..2+B)=idx (as float), [2+B..)=quantized (B x 256).
// Input float dtype (bf16 vs fp32) and node_type width (i32 vs i64) detected
// on-device; both float-dtype kernel variants launched, wrong one early-exits.

#define B_ROWS   131072
#define D_EMB    256
#define QSIZE    128        // codes per quadrant (512/4)
#define TPB      512
#define CHUNK    512        // rows per block
#define NBLK     (B_ROWS / CHUNK)   // 256 blocks == 256 CUs

__device__ __forceinline__ float bf2f(unsigned short u) {
    return __uint_as_float(((unsigned)u) << 16);
}

// Detect (a) input float dtype: for fp32 data the even-indexed ushorts are low
// mantissa halves -> bf16-decoded exponent ~uniform (many outliers); genuine
// bf16 N(0,1) stays near exponent 127. (b) node_type width: int64 values 0..9
// have all-zero odd int32 words; genuine int32 data a.s. has nonzero odds.
__global__ void vq_detect(const unsigned short* cb, const int* nt, int* flag) {
    __shared__ int cnt, odd;
    if (threadIdx.x == 0) { cnt = 0; odd = 0; }
    __syncthreads();
    int c = 0, o = 0;
    for (int i = threadIdx.x; i < 512; i += 64) {
        unsigned short u = cb[2 * i];
        int e = (u >> 7) & 0xFF;
        if (e < 100 || e > 140) c++;
    }
    {
        int v = nt[2 * threadIdx.x + 1];   // odd int32 word
        if (v != 0) o = 1;
    }
    atomicAdd(&cnt, c);
    atomicAdd(&odd, o);
    __syncthreads();
    if (threadIdx.x == 0) {
        flag[0] = (cnt < 50) ? 1 : 0;  // 1 == bf16 float inputs
        flag[1] = (odd == 0) ? 1 : 0;  // 1 == int64 node_type
    }
}

template <int BF16IN>
__global__ __launch_bounds__(TPB, 2) void vq_main(
    const int* __restrict__ nt,
    const void* __restrict__ zraw,
    const void* __restrict__ cbraw,
    float* __restrict__ out,
    double* __restrict__ wsum,
    const int* __restrict__ flag)
{
    if (flag[0] != BF16IN) return;   // uniform early-exit for the wrong-dtype variant
    const int i64 = flag[1];

    // LDS total ~155 KB (<160 KiB) -> 1 block/CU, 256 blocks on 256 CUs.
    __shared__ float  sE[256 * 132];     // codebook quadrant, transposed [k][c], stride 132
    __shared__ float  sZ[128 * 32];      // z tile: 128 rows x 32 k
    __shared__ int    sList[CHUNK];      // chunk rows grouped by quadrant
    __shared__ int    sCnt[4], sPos[4];
    __shared__ int    sTop1[128], sTop2[128];
    __shared__ float  sEe[128];          // ||e||^2 per code of current quadrant
    __shared__ double sRed[TPB / 64];

    const int tid  = threadIdx.x;
    const int row0 = blockIdx.x * CHUNK;

    if (tid < 4) { sCnt[tid] = 0; sPos[tid] = 0; }
    __syncthreads();

    // --- block-local binning of 512 rows into 4 group lists ---
    {
        int t = i64 ? nt[2 * (row0 + tid)] : nt[row0 + tid];
        int g = (t == 5) ? 0 : (t == 6) ? 1 : (t == 7) ? 2 : 3;
        atomicAdd(&sCnt[g], 1);
        __syncthreads();
        int o1 = sCnt[0], o2 = o1 + sCnt[1], o3 = o2 + sCnt[2];
        int offg = (g == 0) ? 0 : (g == 1) ? o1 : (g == 2) ? o2 : o3;
        int p = atomicAdd(&sPos[g], 1);
        sList[offg + p] = row0 + tid;
    }
    __syncthreads();

    int cnt[4], off[4];
    cnt[0] = sCnt[0]; cnt[1] = sCnt[1]; cnt[2] = sCnt[2]; cnt[3] = sCnt[3];
    off[0] = 0; off[1] = cnt[0]; off[2] = off[1] + cnt[1]; off[3] = off[2] + cnt[2];

    const unsigned short* zu  = (const unsigned short*)zraw;
    const unsigned short* cbu = (const unsigned short*)cbraw;
    const float*          zff = (const float*)zraw;
    const float*          cbf = (const float*)cbraw;

    const int ccol  = tid & 31;    // 32 candidate-columns x 4 cands each
    const int rrow  = tid >> 5;    // 16 thread-rows x 8 rows each
    const int c0    = ccol * 4;
    const int rbase = rrow * 8;

    double lacc = 0.0;

    for (int gg = 0; gg < 4; ++gg) {
        const int n = cnt[gg];
        if (n == 0) continue;                       // uniform across block
        __syncthreads();                            // protect sE from prior readers
        // stage quadrant transposed: sE[k*132 + c]
        for (int i = tid; i < QSIZE * D_EMB; i += TPB) {
            int c = i >> 8, k = i & 255;            // consecutive tid -> consecutive k (coalesced)
            float v;
            if (BF16IN) v = bf2f(cbu[(gg * QSIZE + c) * D_EMB + k]);
            else        v = cbf[(gg * QSIZE + c) * D_EMB + k];
            sE[k * 132 + c] = v;
        }
        __syncthreads();
        if (tid < QSIZE) {
            float s = 0.f;
            for (int k = 0; k < D_EMB; ++k) { float v = sE[k * 132 + tid]; s = fmaf(v, v, s); }
            sEe[tid] = s;
        }
        __syncthreads();

        const int ntiles = (n + 127) >> 7;
        for (int tI = 0; tI < ntiles; ++tI) {
            const int tbase = off[gg] + tI * 128;
            const int nrows = min(128, n - tI * 128);

            float acc[8][4];
            #pragma unroll
            for (int r = 0; r < 8; ++r)
                #pragma unroll
                for (int q = 0; q < 4; ++q) acc[r][q] = 0.f;

            for (int kb = 0; kb < 8; ++kb) {
                __syncthreads();
                // stage 128 rows x 32 k of z
                #pragma unroll
                for (int it = 0; it < 2; ++it) {
                    int i = it * TPB + tid;
                    int s = i >> 3, j = i & 7;
                    float4 v = make_float4(0.f, 0.f, 0.f, 0.f);
                    if (s < nrows) {
                        int gr = sList[tbase + s];
                        int eo = gr * D_EMB + kb * 32 + j * 4;
                        if (BF16IN) {
                            ushort4 u4 = *(const ushort4*)(zu + eo);
                            v.x = bf2f(u4.x); v.y = bf2f(u4.y); v.z = bf2f(u4.z); v.w = bf2f(u4.w);
                        } else {
                            v = *(const float4*)(zff + eo);
                        }
                    }
                    *(float4*)&sZ[s * 32 + j * 4] = v;
                }
                __syncthreads();

                #pragma unroll
                for (int k4 = 0; k4 < 8; ++k4) {
                    const int kk = kb * 32 + k4 * 4;
                    const float4 e0 = *(const float4*)&sE[(kk + 0) * 132 + c0];
                    const float4 e1 = *(const float4*)&sE[(kk + 1) * 132 + c0];
                    const float4 e2 = *(const float4*)&sE[(kk + 2) * 132 + c0];
                    const float4 e3 = *(const float4*)&sE[(kk + 3) * 132 + c0];
                    #pragma unroll
                    for (int r = 0; r < 8; ++r) {
                        const float4 zv = *(const float4*)&sZ[(rbase + r) * 32 + k4 * 4];
                        acc[r][0] = fmaf(zv.x, e0.x, fmaf(zv.y, e1.x, fmaf(zv.z, e2.x, fmaf(zv.w, e3.x, acc[r][0]))));
                        acc[r][1] = fmaf(zv.x, e0.y, fmaf(zv.y, e1.y, fmaf(zv.z, e2.y, fmaf(zv.w, e3.y, acc[r][1]))));
                        acc[r][2] = fmaf(zv.x, e0.z, fmaf(zv.y, e1.z, fmaf(zv.z, e2.z, fmaf(zv.w, e3.z, acc[r][2]))));
                        acc[r][3] = fmaf(zv.x, e0.w, fmaf(zv.y, e1.w, fmaf(zv.z, e2.w, fmaf(zv.w, e3.w, acc[r][3]))));
                    }
                }
            }

            // ---- Phase A: per-row top-2 over 128 candidates (fp32 score = ||e||^2 - 2 z.e) ----
            float eq[4] = { sEe[c0], sEe[c0 + 1], sEe[c0 + 2], sEe[c0 + 3] };
            for (int r = 0; r < 8; ++r) {
                float m1 = __builtin_inff(), m2 = __builtin_inff();
                int   i1 = 0x7fffffff,      i2 = 0x7fffffff;
                #pragma unroll
                for (int q = 0; q < 4; ++q) {
                    float sc = eq[q] - 2.f * acc[r][q];
                    int   ci = c0 + q;
                    if (sc < m1 || (sc == m1 && ci < i1)) { m2 = m1; i2 = i1; m1 = sc; i1 = ci; }
                    else if (sc < m2 || (sc == m2 && ci < i2)) { m2 = sc; i2 = ci; }
                }
                #pragma unroll
                for (int d = 1; d < 32; d <<= 1) {   // lanes 0-31 / 32-63 hold distinct rows
                    float b1 = __shfl_xor(m1, d);
                    int  bi1 = __shfl_xor(i1, d);
                    float b2 = __shfl_xor(m2, d);
                    int  bi2 = __shfl_xor(i2, d);
                    if (b1 < m1 || (b1 == m1 && bi1 < i1)) {
                        float om = m1; int oi = i1;
                        m1 = b1; i1 = bi1;
                        if (b2 < om || (b2 == om && bi2 < oi)) { m2 = b2; i2 = bi2; }
                        else                                   { m2 = om; i2 = oi; }
                    } else {
                        if (b1 < m2 || (b1 == m2 && bi1 < i2)) { m2 = b1; i2 = bi1; }
                    }
                }
                if (ccol == 0) { sTop1[rbase + r] = i1; sTop2[rbase + r] = i2; }
            }
            __syncthreads();

            // ---- Phase B: fp64 refinement of top-2, loss, outputs (4 threads/row) ----
            {
                const int s  = tid >> 2;
                const int pq = tid & 3;
                const bool valid = (s < nrows);
                double d1c = 0.0, d2c = 0.0;
                int gr = 0, c1g = 0, c2g = 0;
                if (valid) {
                    gr  = sList[tbase + s];
                    c1g = gg * QSIZE + sTop1[s];
                    c2g = gg * QSIZE + sTop2[s];
                    const int zo = gr  * D_EMB + pq * 64;
                    const int o1 = c1g * D_EMB + pq * 64;
                    const int o2 = c2g * D_EMB + pq * 64;
                    #pragma unroll 4
                    for (int it = 0; it < 16; ++it) {
                        float a[4], p1[4], p2[4];
                        if (BF16IN) {
                            ushort4 uz = *(const ushort4*)(zu  + zo + it * 4);
                            ushort4 u1 = *(const ushort4*)(cbu + o1 + it * 4);
                            ushort4 u2 = *(const ushort4*)(cbu + o2 + it * 4);
                            a[0]=bf2f(uz.x); a[1]=bf2f(uz.y); a[2]=bf2f(uz.z); a[3]=bf2f(uz.w);
                            p1[0]=bf2f(u1.x); p1[1]=bf2f(u1.y); p1[2]=bf2f(u1.z); p1[3]=bf2f(u1.w);
                            p2[0]=bf2f(u2.x); p2[1]=bf2f(u2.y); p2[2]=bf2f(u2.z); p2[3]=bf2f(u2.w);
                        } else {
                            float4 fz = *(const float4*)(zff + zo + it * 4);
                            float4 f1 = *(const float4*)(cbf + o1 + it * 4);
                            float4 f2 = *(const float4*)(cbf + o2 + it * 4);
                            a[0]=fz.x; a[1]=fz.y; a[2]=fz.z; a[3]=fz.w;
                            p1[0]=f1.x; p1[1]=f1.y; p1[2]=f1.z; p1[3]=f1.w;
                            p2[0]=f2.x; p2[1]=f2.y; p2[2]=f2.z; p2[3]=f2.w;
                        }
                        #pragma unroll
                        for (int q = 0; q < 4; ++q) {
                            double e1d = (double)a[q] - (double)p1[q];
                            double e2d = (double)a[q] - (double)p2[q];
                            d1c = fma(e1d, e1d, d1c);
                            d2c = fma(e2d, e2d, d2c);
                        }
                    }
                }
                double t1 = d1c + __shfl_xor(d1c, 1); t1 += __shfl_xor(t1, 2);
                double t2 = d2c + __shfl_xor(d2c, 1); t2 += __shfl_xor(t2, 2);
                if (valid) {
                    bool take1 = (t1 < t2) || (t1 == t2 && c1g < c2g);
                    int  w = take1 ? c1g : c2g;
                    lacc += take1 ? d1c : d2c;       // this thread's chunk of ||z-q||^2
                    // fp32 outputs. Base index == 2 mod 4 -> 8B-aligned: use float2 stores.
                    const int obase = 2 + B_ROWS + gr * D_EMB + pq * 64;
                    #pragma unroll 4
                    for (int it = 0; it < 16; ++it) {
                        float v0, v1, v2, v3;
                        if (BF16IN) {
                            ushort4 u4 = *(const ushort4*)(cbu + w * D_EMB + pq * 64 + it * 4);
                            v0 = bf2f(u4.x); v1 = bf2f(u4.y); v2 = bf2f(u4.z); v3 = bf2f(u4.w);
                        } else {
                            float4 f4 = *(const float4*)(cbf + w * D_EMB + pq * 64 + it * 4);
                            v0 = f4.x; v1 = f4.y; v2 = f4.z; v3 = f4.w;
                        }
                        *(float2*)(out + obase + it * 4)     = make_float2(v0, v1);
                        *(float2*)(out + obase + it * 4 + 2) = make_float2(v2, v3);
                    }
                    if (pq == 0) out[2 + gr] = (float)w;
                }
            }
        } // tiles
    } // groups

    // block loss reduction -> single fp64 atomic per block
    #pragma unroll
    for (int d = 1; d < 64; d <<= 1) lacc += __shfl_xor(lacc, d);
    if ((tid & 63) == 0) sRed[tid >> 6] = lacc;
    __syncthreads();
    if (tid == 0) {
        double s = 0.0;
        #pragma unroll
        for (int i = 0; i < TPB / 64; ++i) s += sRed[i];
        atomicAdd(wsum, s);
    }
}

__global__ void vq_fin(const double* wsum, float* out) {
    if (threadIdx.x == 0 && blockIdx.x == 0) {
        double m = wsum[0] / ((double)B_ROWS * (double)D_EMB);
        out[0] = (float)m;          // vq_loss
        out[1] = (float)(0.25 * m); // commitment_loss (0.25 * same mean)
    }
}

extern "C" void kernel_launch(void* const* d_in, const int* in_sizes, int n_in,
                              void* d_out, int out_size, void* d_ws, size_t ws_size,
                              hipStream_t stream) {
    const int* nt  = (const int*)d_in[0];
    const void* z  = d_in[1];
    const void* cb = d_in[2];
    float* out = (float*)d_out;
    double* wsum = (double*)d_ws;                 // ws[0..8): fp64 loss sum
    int*    flag = (int*)((char*)d_ws + 8);       // ws[8..12): dtype flag, ws[12..16): i64 flag

    hipMemsetAsync(d_ws, 0, 64, stream);
    vq_detect<<<1, 64, 0, stream>>>((const unsigned short*)cb, nt, flag);
    vq_main<1><<<NBLK, TPB, 0, stream>>>(nt, z, cb, out, wsum, flag);  // bf16-input variant
    vq_main<0><<<NBLK, TPB, 0, stream>>>(nt, z, cb, out, wsum, flag);  // fp32-input variant
    vq_fin<<<1, 64, 0, stream>>>(wsum, out);
}

// Round 3
// 684.606 us; speedup vs baseline: 1.0060x; 1.0060x over previous
//
#include <hip/hip_runtime.h>

// VectorQuantizer on MI355X. d_out = FLOAT32 concat:
// [0]=vq_loss, [1]=commitment, [2..2+B)=idx(float), [2+B..)=quantized (B x 256).
// Inputs: node_type int32/int64 (runtime flag), z + codebook bf16 (confirmed;
// fp32 fallback kernel retained, guarded by runtime dtype flag).

#define B_ROWS   131072
#define D_EMB    256
#define QSIZE    128
#define TPB      256
#define CHUNK    256
#define NBLK     (B_ROWS / CHUNK)   // 512 blocks

typedef __attribute__((ext_vector_type(8))) short bf16x8;   // 8 bf16 = 4 VGPRs
typedef __attribute__((ext_vector_type(4))) float f32x4;

__device__ __forceinline__ float bf2f(unsigned short u) {
    return __uint_as_float(((unsigned)u) << 16);
}

// flag[0]=1 if float inputs are bf16; flag[1]=1 if node_type is int64.
__global__ void vq_detect(const unsigned short* cb, const int* nt, int* flag) {
    __shared__ int cnt, odd;
    if (threadIdx.x == 0) { cnt = 0; odd = 0; }
    __syncthreads();
    int c = 0, o = 0;
    for (int i = threadIdx.x; i < 512; i += 64) {
        unsigned short u = cb[2 * i];
        int e = (u >> 7) & 0xFF;
        if (e < 100 || e > 140) c++;
    }
    if (nt[2 * threadIdx.x + 1] != 0) o = 1;
    atomicAdd(&cnt, c);
    atomicAdd(&odd, o);
    __syncthreads();
    if (threadIdx.x == 0) {
        flag[0] = (cnt < 50) ? 1 : 0;
        flag[1] = (odd == 0) ? 1 : 0;
    }
}

// ============================ bf16 MFMA path ============================
__global__ __launch_bounds__(TPB, 2) void vq_mfma(
    const int* __restrict__ nt,
    const unsigned short* __restrict__ zu,
    const unsigned short* __restrict__ cbu,
    float* __restrict__ out,
    double* __restrict__ wsum,
    const int* __restrict__ flag)
{
    if (flag[0] != 1) return;
    const int i64 = flag[1];

    __shared__ int    sList[CHUNK];
    __shared__ int    sCnt[4], sPos[4];
    __shared__ int    sTiles[72];
    __shared__ int    sNT;
    __shared__ float  sEe[512];          // ||e||^2 for all 512 codes (fp32)
    __shared__ int2   sT[4][16];         // per-wave top-2 per row
    __shared__ double sRed[4];

    const int tid  = threadIdx.x;
    const int row0 = blockIdx.x * CHUNK;

    if (tid < 4) { sCnt[tid] = 0; sPos[tid] = 0; }
    __syncthreads();

    // --- bin 256 rows into 4 group lists ---
    {
        int t = i64 ? nt[2 * (row0 + tid)] : nt[row0 + tid];
        int g = (t == 5) ? 0 : (t == 6) ? 1 : (t == 7) ? 2 : 3;
        atomicAdd(&sCnt[g], 1);
        __syncthreads();
        int o1 = sCnt[0], o2 = o1 + sCnt[1], o3 = o2 + sCnt[2];
        int offg = (g == 0) ? 0 : (g == 1) ? o1 : (g == 2) ? o2 : o3;
        int p = atomicAdd(&sPos[g], 1);
        sList[offg + p] = row0 + tid;
    }
    __syncthreads();

    // --- thread 0 builds tile list; everyone computes codebook norms ---
    if (tid == 0) {
        int c = 0, offg = 0;
        for (int g = 0; g < 4; ++g) {
            int n = sCnt[g];
            for (int b = 0; b < n; b += 16) {
                int nr = (n - b < 16) ? (n - b) : 16;
                sTiles[c++] = (g << 14) | ((offg + b) << 5) | nr;
            }
            offg += n;
        }
        sNT = c;
    }
    for (int cc = tid; cc < 512; cc += TPB) {
        const unsigned short* p = cbu + cc * 256;
        float s = 0.f;
        for (int i = 0; i < 32; ++i) {
            uint4 w = *(const uint4*)(p + i * 8);
            float v0 = bf2f((unsigned short)w.x), v1 = bf2f((unsigned short)(w.x >> 16));
            float v2 = bf2f((unsigned short)w.y), v3 = bf2f((unsigned short)(w.y >> 16));
            float v4 = bf2f((unsigned short)w.z), v5 = bf2f((unsigned short)(w.z >> 16));
            float v6 = bf2f((unsigned short)w.w), v7 = bf2f((unsigned short)(w.w >> 16));
            s = fmaf(v0,v0,fmaf(v1,v1,fmaf(v2,v2,fmaf(v3,v3,s))));
            s = fmaf(v4,v4,fmaf(v5,v5,fmaf(v6,v6,fmaf(v7,v7,s))));
        }
        sEe[cc] = s;
    }
    __syncthreads();

    const int wave = tid >> 6;
    const int lane = tid & 63;
    const int col  = lane & 15;
    const int quad = lane >> 4;
    const int nt_  = sNT;

    double lacc = 0.0;

    for (int ti = wave; ti < nt_; ti += 4) {
        const int td = sTiles[ti];
        const int g  = td >> 14;
        const int tb = (td >> 5) & 0x1FF;
        const int nr = td & 0x1F;

        // ---- scoring GEMM: 16 rows x 128 codes, K=256, bf16 MFMA ----
        const int rowA = sList[tb + ((col < nr) ? col : (nr - 1))];
        const unsigned short* za = zu  + rowA * 256 + quad * 8;            // A: m=col, k=quad*8+j
        const unsigned short* ba = cbu + (g * 128 + col) * 256 + quad * 8; // B: n=col, k=quad*8+j

        f32x4 acc[8];
        #pragma unroll
        for (int t = 0; t < 8; ++t) acc[t] = (f32x4){0.f, 0.f, 0.f, 0.f};

        #pragma unroll
        for (int c = 0; c < 8; ++c) {
            bf16x8 a = *(const bf16x8*)(za + c * 32);
            #pragma unroll
            for (int t = 0; t < 8; ++t) {
                bf16x8 b = *(const bf16x8*)(ba + t * 4096 + c * 32);  // t*16 codes * 256
                acc[t] = __builtin_amdgcn_mfma_f32_16x16x32_bf16(a, b, acc[t], 0, 0, 0);
            }
        }

        // ---- per-row top-2 (score = ||e||^2 - 2 z.e), C-layout: row=quad*4+r, col=lane&15 ----
        float e8[8];
        #pragma unroll
        for (int t = 0; t < 8; ++t) e8[t] = sEe[g * 128 + t * 16 + col];

        #pragma unroll
        for (int r = 0; r < 4; ++r) {
            float m1 = __builtin_inff(), m2 = __builtin_inff();
            int   i1 = 0x7fffffff,      i2 = 0x7fffffff;
            #pragma unroll
            for (int t = 0; t < 8; ++t) {
                float sc = e8[t] - 2.f * acc[t][r];
                int   ci = t * 16 + col;
                if (sc < m1 || (sc == m1 && ci < i1)) { m2 = m1; i2 = i1; m1 = sc; i1 = ci; }
                else if (sc < m2 || (sc == m2 && ci < i2)) { m2 = sc; i2 = ci; }
            }
            #pragma unroll
            for (int d = 1; d < 16; d <<= 1) {   // reduce across the 16 col-lanes
                float b1 = __shfl_xor(m1, d);
                int  bi1 = __shfl_xor(i1, d);
                float b2 = __shfl_xor(m2, d);
                int  bi2 = __shfl_xor(i2, d);
                if (b1 < m1 || (b1 == m1 && bi1 < i1)) {
                    float om = m1; int oi = i1;
                    m1 = b1; i1 = bi1;
                    if (b2 < om || (b2 == om && bi2 < oi)) { m2 = b2; i2 = bi2; }
                    else                                   { m2 = om; i2 = oi; }
                } else {
                    if (b1 < m2 || (b1 == m2 && bi1 < i2)) { m2 = b1; i2 = bi1; }
                }
            }
            if (col == 0) sT[wave][quad * 4 + r] = make_int2(i1, i2);
        }

        // ---- fp64 refine of top-2 + outputs (4 lanes per row) ----
        {
            const int s  = lane >> 2;
            const int pq = lane & 3;
            const bool valid = (s < nr);
            double d1c = 0.0, d2c = 0.0;
            int gr = 0, c1 = 0, c2 = 0;
            if (valid) {
                gr = sList[tb + s];
                int2 tt = sT[wave][s];
                c1 = g * 128 + tt.x;
                c2 = g * 128 + tt.y;
                const unsigned short* zp = zu  + gr * 256 + pq * 64;
                const unsigned short* p1 = cbu + c1 * 256 + pq * 64;
                const unsigned short* p2 = cbu + c2 * 256 + pq * 64;
                #pragma unroll 4
                for (int it = 0; it < 16; ++it) {
                    ushort4 ua = *(const ushort4*)(zp + it * 4);
                    ushort4 u1 = *(const ushort4*)(p1 + it * 4);
                    ushort4 u2 = *(const ushort4*)(p2 + it * 4);
                    float a0 = bf2f(ua.x), a1 = bf2f(ua.y), a2 = bf2f(ua.z), a3 = bf2f(ua.w);
                    float q0 = bf2f(u1.x), q1 = bf2f(u1.y), q2 = bf2f(u1.z), q3 = bf2f(u1.w);
                    float w0 = bf2f(u2.x), w1 = bf2f(u2.y), w2 = bf2f(u2.z), w3 = bf2f(u2.w);
                    double e;
                    e = (double)a0 - (double)q0; d1c = fma(e, e, d1c);
                    e = (double)a1 - (double)q1; d1c = fma(e, e, d1c);
                    e = (double)a2 - (double)q2; d1c = fma(e, e, d1c);
                    e = (double)a3 - (double)q3; d1c = fma(e, e, d1c);
                    e = (double)a0 - (double)w0; d2c = fma(e, e, d2c);
                    e = (double)a1 - (double)w1; d2c = fma(e, e, d2c);
                    e = (double)a2 - (double)w2; d2c = fma(e, e, d2c);
                    e = (double)a3 - (double)w3; d2c = fma(e, e, d2c);
                }
            }
            double t1 = d1c + __shfl_xor(d1c, 1); t1 += __shfl_xor(t1, 2);
            double t2 = d2c + __shfl_xor(d2c, 1); t2 += __shfl_xor(t2, 2);
            if (valid) {
                bool take1 = (t1 < t2) || (t1 == t2 && c1 < c2);
                int  w = take1 ? c1 : c2;
                lacc += take1 ? d1c : d2c;
                const unsigned short* pw = cbu + w * 256 + pq * 64;
                const int obase = 2 + B_ROWS + gr * 256 + pq * 64;   // ==2 mod 4 -> 8B aligned
                #pragma unroll 4
                for (int it = 0; it < 16; ++it) {
                    ushort4 u4 = *(const ushort4*)(pw + it * 4);
                    *(float2*)(out + obase + it * 4)     = make_float2(bf2f(u4.x), bf2f(u4.y));
                    *(float2*)(out + obase + it * 4 + 2) = make_float2(bf2f(u4.z), bf2f(u4.w));
                }
                if (pq == 0) out[2 + gr] = (float)w;
            }
        }
    }

    #pragma unroll
    for (int d = 1; d < 64; d <<= 1) lacc += __shfl_xor(lacc, d);
    if (lane == 0) sRed[wave] = lacc;
    __syncthreads();
    if (tid == 0) atomicAdd(wsum, sRed[0] + sRed[1] + sRed[2] + sRed[3]);
}

// ===================== fp32-input fallback (round-2 kernel) =====================
__global__ __launch_bounds__(512, 2) void vq_main_f32(
    const int* __restrict__ nt,
    const float* __restrict__ zff,
    const float* __restrict__ cbf,
    float* __restrict__ out,
    double* __restrict__ wsum,
    const int* __restrict__ flag)
{
    if (flag[0] != 0) return;
    const int i64 = flag[1];

    __shared__ float  sE[256 * 132];
    __shared__ float  sZ[128 * 32];
    __shared__ int    sList[512];
    __shared__ int    sCnt[4], sPos[4];
    __shared__ int    sTop1[128], sTop2[128];
    __shared__ float  sEe[128];
    __shared__ double sRed[8];

    const int tid  = threadIdx.x;
    const int row0 = blockIdx.x * 512;

    if (tid < 4) { sCnt[tid] = 0; sPos[tid] = 0; }
    __syncthreads();
    {
        int t = i64 ? nt[2 * (row0 + tid)] : nt[row0 + tid];
        int g = (t == 5) ? 0 : (t == 6) ? 1 : (t == 7) ? 2 : 3;
        atomicAdd(&sCnt[g], 1);
        __syncthreads();
        int o1 = sCnt[0], o2 = o1 + sCnt[1], o3 = o2 + sCnt[2];
        int offg = (g == 0) ? 0 : (g == 1) ? o1 : (g == 2) ? o2 : o3;
        int p = atomicAdd(&sPos[g], 1);
        sList[offg + p] = row0 + tid;
    }
    __syncthreads();

    int cnt[4], off[4];
    cnt[0] = sCnt[0]; cnt[1] = sCnt[1]; cnt[2] = sCnt[2]; cnt[3] = sCnt[3];
    off[0] = 0; off[1] = cnt[0]; off[2] = off[1] + cnt[1]; off[3] = off[2] + cnt[2];

    const int ccol = tid & 31, rrow = tid >> 5;
    const int c0 = ccol * 4, rbase = rrow * 8;
    double lacc = 0.0;

    for (int gg = 0; gg < 4; ++gg) {
        const int n = cnt[gg];
        if (n == 0) continue;
        __syncthreads();
        for (int i = tid; i < QSIZE * D_EMB; i += 512) {
            int c = i >> 8, k = i & 255;
            sE[k * 132 + c] = cbf[(gg * QSIZE + c) * D_EMB + k];
        }
        __syncthreads();
        if (tid < QSIZE) {
            float s = 0.f;
            for (int k = 0; k < D_EMB; ++k) { float v = sE[k * 132 + tid]; s = fmaf(v, v, s); }
            sEe[tid] = s;
        }
        __syncthreads();

        const int ntiles = (n + 127) >> 7;
        for (int tI = 0; tI < ntiles; ++tI) {
            const int tbase = off[gg] + tI * 128;
            const int nrows = min(128, n - tI * 128);
            float acc[8][4];
            #pragma unroll
            for (int r = 0; r < 8; ++r)
                #pragma unroll
                for (int q = 0; q < 4; ++q) acc[r][q] = 0.f;

            for (int kb = 0; kb < 8; ++kb) {
                __syncthreads();
                #pragma unroll
                for (int it = 0; it < 2; ++it) {
                    int i = it * 512 + tid;
                    int s = i >> 3, j = i & 7;
                    float4 v = make_float4(0.f, 0.f, 0.f, 0.f);
                    if (s < nrows) {
                        int gr = sList[tbase + s];
                        v = *(const float4*)(zff + gr * D_EMB + kb * 32 + j * 4);
                    }
                    *(float4*)&sZ[s * 32 + j * 4] = v;
                }
                __syncthreads();
                #pragma unroll
                for (int k4 = 0; k4 < 8; ++k4) {
                    const int kk = kb * 32 + k4 * 4;
                    const float4 e0 = *(const float4*)&sE[(kk + 0) * 132 + c0];
                    const float4 e1 = *(const float4*)&sE[(kk + 1) * 132 + c0];
                    const float4 e2 = *(const float4*)&sE[(kk + 2) * 132 + c0];
                    const float4 e3 = *(const float4*)&sE[(kk + 3) * 132 + c0];
                    #pragma unroll
                    for (int r = 0; r < 8; ++r) {
                        const float4 zv = *(const float4*)&sZ[(rbase + r) * 32 + k4 * 4];
                        acc[r][0] = fmaf(zv.x, e0.x, fmaf(zv.y, e1.x, fmaf(zv.z, e2.x, fmaf(zv.w, e3.x, acc[r][0]))));
                        acc[r][1] = fmaf(zv.x, e0.y, fmaf(zv.y, e1.y, fmaf(zv.z, e2.y, fmaf(zv.w, e3.y, acc[r][1]))));
                        acc[r][2] = fmaf(zv.x, e0.z, fmaf(zv.y, e1.z, fmaf(zv.z, e2.z, fmaf(zv.w, e3.z, acc[r][2]))));
                        acc[r][3] = fmaf(zv.x, e0.w, fmaf(zv.y, e1.w, fmaf(zv.z, e2.w, fmaf(zv.w, e3.w, acc[r][3]))));
                    }
                }
            }

            float eq[4] = { sEe[c0], sEe[c0 + 1], sEe[c0 + 2], sEe[c0 + 3] };
            for (int r = 0; r < 8; ++r) {
                float m1 = __builtin_inff(), m2 = __builtin_inff();
                int   i1 = 0x7fffffff,      i2 = 0x7fffffff;
                #pragma unroll
                for (int q = 0; q < 4; ++q) {
                    float sc = eq[q] - 2.f * acc[r][q];
                    int   ci = c0 + q;
                    if (sc < m1 || (sc == m1 && ci < i1)) { m2 = m1; i2 = i1; m1 = sc; i1 = ci; }
                    else if (sc < m2 || (sc == m2 && ci < i2)) { m2 = sc; i2 = ci; }
                }
                #pragma unroll
                for (int d = 1; d < 32; d <<= 1) {
                    float b1 = __shfl_xor(m1, d);
                    int  bi1 = __shfl_xor(i1, d);
                    float b2 = __shfl_xor(m2, d);
                    int  bi2 = __shfl_xor(i2, d);
                    if (b1 < m1 || (b1 == m1 && bi1 < i1)) {
                        float om = m1; int oi = i1;
                        m1 = b1; i1 = bi1;
                        if (b2 < om || (b2 == om && bi2 < oi)) { m2 = b2; i2 = bi2; }
                        else                                   { m2 = om; i2 = oi; }
                    } else {
                        if (b1 < m2 || (b1 == m2 && bi1 < i2)) { m2 = b1; i2 = bi1; }
                    }
                }
                if (ccol == 0) { sTop1[rbase + r] = i1; sTop2[rbase + r] = i2; }
            }
            __syncthreads();

            {
                const int s  = tid >> 2;
                const int pq = tid & 3;
                const bool valid = (s < nrows);
                double d1c = 0.0, d2c = 0.0;
                int gr = 0, c1g = 0, c2g = 0;
                if (valid) {
                    gr  = sList[tbase + s];
                    c1g = gg * QSIZE + sTop1[s];
                    c2g = gg * QSIZE + sTop2[s];
                    #pragma unroll 4
                    for (int it = 0; it < 16; ++it) {
                        float4 fz = *(const float4*)(zff + gr  * D_EMB + pq * 64 + it * 4);
                        float4 f1 = *(const float4*)(cbf + c1g * D_EMB + pq * 64 + it * 4);
                        float4 f2 = *(const float4*)(cbf + c2g * D_EMB + pq * 64 + it * 4);
                        double e;
                        e = (double)fz.x - (double)f1.x; d1c = fma(e, e, d1c);
                        e = (double)fz.y - (double)f1.y; d1c = fma(e, e, d1c);
                        e = (double)fz.z - (double)f1.z; d1c = fma(e, e, d1c);
                        e = (double)fz.w - (double)f1.w; d1c = fma(e, e, d1c);
                        e = (double)fz.x - (double)f2.x; d2c = fma(e, e, d2c);
                        e = (double)fz.y - (double)f2.y; d2c = fma(e, e, d2c);
                        e = (double)fz.z - (double)f2.z; d2c = fma(e, e, d2c);
                        e = (double)fz.w - (double)f2.w; d2c = fma(e, e, d2c);
                    }
                }
                double t1 = d1c + __shfl_xor(d1c, 1); t1 += __shfl_xor(t1, 2);
                double t2 = d2c + __shfl_xor(d2c, 1); t2 += __shfl_xor(t2, 2);
                if (valid) {
                    bool take1 = (t1 < t2) || (t1 == t2 && c1g < c2g);
                    int  w = take1 ? c1g : c2g;
                    lacc += take1 ? d1c : d2c;
                    const int obase = 2 + B_ROWS + gr * D_EMB + pq * 64;
                    #pragma unroll 4
                    for (int it = 0; it < 16; ++it) {
                        float4 f4 = *(const float4*)(cbf + w * D_EMB + pq * 64 + it * 4);
                        *(float2*)(out + obase + it * 4)     = make_float2(f4.x, f4.y);
                        *(float2*)(out + obase + it * 4 + 2) = make_float2(f4.z, f4.w);
                    }
                    if (pq == 0) out[2 + gr] = (float)w;
                }
            }
        }
    }

    #pragma unroll
    for (int d = 1; d < 64; d <<= 1) lacc += __shfl_xor(lacc, d);
    if ((tid & 63) == 0) sRed[tid >> 6] = lacc;
    __syncthreads();
    if (tid == 0) {
        double s = 0.0;
        #pragma unroll
        for (int i = 0; i < 8; ++i) s += sRed[i];
        atomicAdd(wsum, s);
    }
}

__global__ void vq_fin(const double* wsum, float* out) {
    if (threadIdx.x == 0 && blockIdx.x == 0) {
        double m = wsum[0] / ((double)B_ROWS * (double)D_EMB);
        out[0] = (float)m;
        out[1] = (float)(0.25 * m);
    }
}

extern "C" void kernel_launch(void* const* d_in, const int* in_sizes, int n_in,
                              void* d_out, int out_size, void* d_ws, size_t ws_size,
                              hipStream_t stream) {
    const int* nt  = (const int*)d_in[0];
    const void* z  = d_in[1];
    const void* cb = d_in[2];
    float* out = (float*)d_out;
    double* wsum = (double*)d_ws;
    int*    flag = (int*)((char*)d_ws + 8);

    hipMemsetAsync(d_ws, 0, 64, stream);
    vq_detect<<<1, 64, 0, stream>>>((const unsigned short*)cb, nt, flag);
    vq_mfma<<<NBLK, TPB, 0, stream>>>(nt, (const unsigned short*)z,
                                      (const unsigned short*)cb, out, wsum, flag);
    vq_main_f32<<<256, 512, 0, stream>>>(nt, (const float*)z, (const float*)cb,
                                         out, wsum, flag);
    vq_fin<<<1, 64, 0, stream>>>(wsum, out);
}